// Round 1
// baseline (243.196 us; speedup 1.0000x reference)
//
#include <hip/hip_runtime.h>
#include <hip/hip_bf16.h>

// Problem constants (from reference)
#define BB 2
#define TT 1024
#define CC 2048
#define NCH 8
#define KLAT 32
#define NKV 4
#define NREP 4
#define DD 128
#define MROWS (BB*TT)          // 2048
#define CSROWS (BB*NCH*KLAT)   // 512

typedef unsigned short u16;
typedef __attribute__((ext_vector_type(8))) short bf16x8;   // 8 bf16 (4 VGPRs) — MFMA A/B frag
typedef __attribute__((ext_vector_type(4))) float f32x4;    // MFMA C/D frag
typedef __attribute__((ext_vector_type(8))) u16 u16x8;

__device__ __forceinline__ u16 f2bf(float f) {
    unsigned int u = __builtin_bit_cast(unsigned int, f);
    u = (u + 0x7FFFu + ((u >> 16) & 1u)) >> 16;   // RNE; inputs are finite
    return (u16)u;
}

// ---------------- elementwise fp32 -> bf16 ----------------
__global__ void __launch_bounds__(256)
cvt_bf16_kernel(const float* __restrict__ in, u16* __restrict__ out, int n) {
    int i = (blockIdx.x * 256 + threadIdx.x) * 8;
    if (i >= n) return;
    float4 a = *(const float4*)(in + i);
    float4 b = *(const float4*)(in + i + 4);
    u16x8 o;
    o[0]=f2bf(a.x); o[1]=f2bf(a.y); o[2]=f2bf(a.z); o[3]=f2bf(a.w);
    o[4]=f2bf(b.x); o[5]=f2bf(b.y); o[6]=f2bf(b.z); o[7]=f2bf(b.w);
    *(u16x8*)(out + i) = o;
}

// ---------------- transpose + convert: in (R x C) fp32 -> out (C x R) bf16 ----------------
__global__ void __launch_bounds__(256)
tcvt_kernel(const float* __restrict__ in, u16* __restrict__ out, int R, int C) {
    __shared__ u16 tile[64][65];
    const int c0 = blockIdx.x * 64;
    const int r0 = blockIdx.y * 64;
    const int tid = threadIdx.x;
    const int tx = tid & 15;    // col group (x4 floats)
    const int ty = tid >> 4;    // row within pass
#pragma unroll
    for (int p = 0; p < 4; ++p) {
        int r = p * 16 + ty;
        float4 v = *(const float4*)(in + (size_t)(r0 + r) * C + c0 + tx * 4);
        tile[tx*4+0][r] = f2bf(v.x);
        tile[tx*4+1][r] = f2bf(v.y);
        tile[tx*4+2][r] = f2bf(v.z);
        tile[tx*4+3][r] = f2bf(v.w);
    }
    __syncthreads();
    const int oc = tid >> 2;    // out row (= input col), 0..63
    const int op = tid & 3;     // 16-elem chunk along r
    u16* dst = out + (size_t)(c0 + oc) * R + r0 + op * 16;
    u16x8 v0, v1;
#pragma unroll
    for (int j = 0; j < 8; ++j) { v0[j] = tile[oc][op*16 + j]; v1[j] = tile[oc][op*16 + 8 + j]; }
    *(u16x8*)dst = v0;
    *(u16x8*)(dst + 8) = v1;
}

// ---------------- bf16 GEMM, both operands K-contiguous (B pre-transposed) ----------------
// A: M x K row-major bf16; Bt: N x K row-major bf16; C: M x N fp32.
// m97-style 2-barrier K-loop, 16x16x32 MFMA, BK=32, 256 threads (4 waves, 2x2).
template<int BM, int BN, bool ATOMIC, bool GATE>
__global__ void __launch_bounds__(256)
gemm_bt_kernel(const u16* __restrict__ A, const u16* __restrict__ Bt,
               float* __restrict__ C, int M, int N, int K, int kChunk,
               const float* __restrict__ gate)
{
    constexpr int BK = 32;
    __shared__ u16 As[BM * BK];
    __shared__ u16 Bs[BN * BK];
    const int tid  = threadIdx.x;
    const int m0   = blockIdx.x * BM;
    const int n0   = blockIdx.y * BN;
    const int kbeg = blockIdx.z * kChunk;
    const int wave = tid >> 6;
    const int lane = tid & 63;
    constexpr int WM = BM / 2, WN = BN / 2;
    constexpr int MI = WM / 16, NI = WN / 16;
    const int wm = (wave & 1) * WM;
    const int wn = (wave >> 1) * WN;
    const int ml = lane & 15;
    const int quad = lane >> 4;

    f32x4 acc[MI][NI];
#pragma unroll
    for (int i = 0; i < MI; ++i)
#pragma unroll
        for (int j = 0; j < NI; ++j) acc[i][j] = (f32x4){0.f, 0.f, 0.f, 0.f};

    // staging: each thread moves 16B per round; round = 64 rows of the tile
    constexpr int RA = (BM * BK) / 2048;   // rounds for A (2 for BM=128, 1 for 64)
    constexpr int RB = (BN * BK) / 2048;
    const int rstag = tid >> 2;            // row 0..63 within round
    const int kcst  = (tid & 3) * 8;       // k-chunk within row
    const u16* aptr = A  + (size_t)(m0 + rstag) * K + kbeg + kcst;
    const u16* bptr = Bt + (size_t)(n0 + rstag) * K + kbeg + kcst;

    u16x8 av[RA], bv[RB];
#pragma unroll
    for (int p = 0; p < RA; ++p) av[p] = *(const u16x8*)(aptr + (size_t)p * 64 * K);
#pragma unroll
    for (int p = 0; p < RB; ++p) bv[p] = *(const u16x8*)(bptr + (size_t)p * 64 * K);

    for (int k0 = 0; k0 < kChunk; k0 += BK) {
        __syncthreads();
#pragma unroll
        for (int p = 0; p < RA; ++p) *(u16x8*)&As[p * 2048 + tid * 8] = av[p];
#pragma unroll
        for (int p = 0; p < RB; ++p) *(u16x8*)&Bs[p * 2048 + tid * 8] = bv[p];
        __syncthreads();
        if (k0 + BK < kChunk) {   // prefetch next tile into regs, overlaps MFMA below
#pragma unroll
            for (int p = 0; p < RA; ++p) av[p] = *(const u16x8*)(aptr + (size_t)p * 64 * K + k0 + BK);
#pragma unroll
            for (int p = 0; p < RB; ++p) bv[p] = *(const u16x8*)(bptr + (size_t)p * 64 * K + k0 + BK);
        }
        bf16x8 afr[MI], bfr[NI];
#pragma unroll
        for (int i = 0; i < MI; ++i)
            afr[i] = *(const bf16x8*)&As[(wm + i * 16 + ml) * BK + quad * 8];
#pragma unroll
        for (int j = 0; j < NI; ++j)
            bfr[j] = *(const bf16x8*)&Bs[(wn + j * 16 + ml) * BK + quad * 8];
#pragma unroll
        for (int i = 0; i < MI; ++i)
#pragma unroll
            for (int j = 0; j < NI; ++j)
                acc[i][j] = __builtin_amdgcn_mfma_f32_16x16x32_bf16(afr[i], bfr[j], acc[i][j], 0, 0, 0);
    }

    float scl = 1.0f;
    if (GATE) scl = tanhf(gate[0]);
    // C/D layout (verified m89/m91): col = lane&15, row = quad*4 + reg
#pragma unroll
    for (int i = 0; i < MI; ++i)
#pragma unroll
        for (int j = 0; j < NI; ++j)
#pragma unroll
            for (int rr = 0; rr < 4; ++rr) {
                int gr = m0 + wm + i * 16 + quad * 4 + rr;
                int gc = n0 + wn + j * 16 + ml;
                float val = acc[i][j][rr];
                if (GATE) val *= scl;
                if (ATOMIC) atomicAdd(&C[(size_t)gr * N + gc], val);
                else        C[(size_t)gr * N + gc] = val;
            }
}

// ---------------- tiny-K attention, fp32, one block per token ----------------
// q: (B*T, 2048) fp32 as (g,r,d); kv: (B*8*32, 1024) fp32, cols [k(g,d) | v(g,d)]
// y: (B*T, 2048) bf16. wave = g; 16-lane subgroup per (g,r); lane owns 8 of D=128.
__global__ void __launch_bounds__(256)
attn_kernel(const float* __restrict__ q, const float* __restrict__ kv,
            const int* __restrict__ cmask, u16* __restrict__ y)
{
    const int bt  = blockIdx.x;
    const int b   = bt >> 10;           // T = 1024
    const int tid = threadIdx.x;
    const int g   = tid >> 6;
    const int l16 = tid & 15;
    const int n   = cmask[bt];

    const float* qp = q + (size_t)bt * 2048 + tid * 8;   // tid*8 == g*512+r*128+l16*8
    float qv[8];
    {
        float4 a = *(const float4*)qp;
        float4 c = *(const float4*)(qp + 4);
        qv[0]=a.x; qv[1]=a.y; qv[2]=a.z; qv[3]=a.w;
        qv[4]=c.x; qv[5]=c.y; qv[6]=c.z; qv[7]=c.w;
    }
    const float* kbase = kv + (size_t)((b * 8 + n) * 32) * 1024 + g * 128 + l16 * 8;

    float sc[32];
#pragma unroll
    for (int kk = 0; kk < 32; ++kk) {
        const float* kp = kbase + kk * 1024;
        float4 a = *(const float4*)kp;
        float4 c = *(const float4*)(kp + 4);
        sc[kk] = qv[0]*a.x + qv[1]*a.y + qv[2]*a.z + qv[3]*a.w
               + qv[4]*c.x + qv[5]*c.y + qv[6]*c.z + qv[7]*c.w;
    }
    const float scale = 0.088388347648318447f;  // 1/sqrt(128)
#pragma unroll
    for (int kk = 0; kk < 32; ++kk) {
        float s = sc[kk];
        s += __shfl_xor(s, 1);
        s += __shfl_xor(s, 2);
        s += __shfl_xor(s, 4);
        s += __shfl_xor(s, 8);
        sc[kk] = s * scale;
    }
    float mx = sc[0];
#pragma unroll
    for (int kk = 1; kk < 32; ++kk) mx = fmaxf(mx, sc[kk]);
    float sum = 0.f;
#pragma unroll
    for (int kk = 0; kk < 32; ++kk) { sc[kk] = __expf(sc[kk] - mx); sum += sc[kk]; }
    const float inv = 1.0f / sum;

    float acc[8] = {0,0,0,0,0,0,0,0};
    const float* vbase = kbase + 512;
#pragma unroll
    for (int kk = 0; kk < 32; ++kk) {
        const float* vp = vbase + kk * 1024;
        float4 a = *(const float4*)vp;
        float4 c = *(const float4*)(vp + 4);
        const float w = sc[kk];
        acc[0] += w*a.x; acc[1] += w*a.y; acc[2] += w*a.z; acc[3] += w*a.w;
        acc[4] += w*c.x; acc[5] += w*c.y; acc[6] += w*c.z; acc[7] += w*c.w;
    }
    u16x8 o;
#pragma unroll
    for (int j = 0; j < 8; ++j) o[j] = f2bf(acc[j] * inv);
    *(u16x8*)(y + (size_t)bt * 2048 + tid * 8) = o;
}

extern "C" void kernel_launch(void* const* d_in, const int* in_sizes, int n_in,
                              void* d_out, int out_size, void* d_ws, size_t ws_size,
                              hipStream_t stream) {
    const float* x    = (const float*)d_in[0];
    const float* cs   = (const float*)d_in[1];
    const int*   cm   = (const int*)d_in[2];
    const float* Wq   = (const float*)d_in[3];
    const float* Wk   = (const float*)d_in[4];
    const float* Wv   = (const float*)d_in[5];
    const float* Wo   = (const float*)d_in[6];
    const float* gate = (const float*)d_in[7];
    float* out = (float*)d_out;

    // workspace layout (all 16B aligned)
    char* w = (char*)d_ws;
    u16* xb   = (u16*)w;  w += (size_t)MROWS * CC * 2;        // x bf16
    u16* wqt  = (u16*)w;  w += (size_t)CC * CC * 2;           // Wq^T bf16 (2048 x 2048)
    u16* wkvt = (u16*)w;  w += (size_t)1024 * CC * 2;         // [Wk^T ; Wv^T] (1024 x 2048)
    u16* wot  = (u16*)w;  w += (size_t)CC * CC * 2;           // Wo^T
    u16* csb  = (u16*)w;  w += (size_t)CSROWS * CC * 2;       // channel_states bf16
    u16* yb   = (u16*)w;  w += (size_t)MROWS * CC * 2;        // attention output bf16
    float* q  = (float*)w; w += (size_t)MROWS * CC * 4;       // q fp32
    float* kv = (float*)w; w += (size_t)CSROWS * 1024 * 4;    // [k|v] fp32

    // zero kv (split-K atomic accumulation target)
    hipMemsetAsync(kv, 0, (size_t)CSROWS * 1024 * 4, stream);

    // converts
    cvt_bf16_kernel<<<(MROWS * CC) / 2048, 256, 0, stream>>>(x, xb, MROWS * CC);
    cvt_bf16_kernel<<<(CSROWS * CC) / 2048, 256, 0, stream>>>(cs, csb, CSROWS * CC);
    // weight transposes (fp32 KxN -> bf16 NxK)
    tcvt_kernel<<<dim3(CC / 64, CC / 64), 256, 0, stream>>>(Wq, wqt, CC, CC);
    tcvt_kernel<<<dim3(512 / 64, CC / 64), 256, 0, stream>>>(Wk, wkvt, CC, 512);
    tcvt_kernel<<<dim3(512 / 64, CC / 64), 256, 0, stream>>>(Wv, wkvt + (size_t)512 * CC, CC, 512);
    tcvt_kernel<<<dim3(CC / 64, CC / 64), 256, 0, stream>>>(Wo, wot, CC, CC);

    // q = x @ Wq   (2048 x 2048 x 2048)
    gemm_bt_kernel<128, 128, false, false><<<dim3(MROWS / 128, CC / 128), 256, 0, stream>>>(
        xb, wqt, q, MROWS, CC, CC, CC, nullptr);
    // kv = cs @ [Wk|Wv]  (512 x 1024 x 2048), split-K=4 atomic
    gemm_bt_kernel<64, 64, true, false><<<dim3(CSROWS / 64, 1024 / 64, 4), 256, 0, stream>>>(
        csb, wkvt, kv, CSROWS, 1024, CC, CC / 4, nullptr);
    // attention -> y (bf16)
    attn_kernel<<<MROWS, 256, 0, stream>>>(q, kv, cm, yb);
    // out = (y @ Wo) * tanh(gate)
    gemm_bt_kernel<128, 128, false, true><<<dim3(MROWS / 128, CC / 128), 256, 0, stream>>>(
        yb, wot, out, MROWS, CC, CC, CC, gate);
}